// Round 2
// baseline (361.558 us; speedup 1.0000x reference)
//
#include <hip/hip_runtime.h>

typedef float  f32x4 __attribute__((ext_vector_type(4)));
typedef short  s16x8 __attribute__((ext_vector_type(8)));
typedef unsigned short u16;

#define HDIM 1024
#define BATCH 32
#define SEQ 2048
#define NROWS (BATCH*SEQ)   // 65536

#define BM 128
#define BN 128
#define BK 32
#define NKT (HDIM/BK)       // 32

#define GLD16(gp, lp) __builtin_amdgcn_global_load_lds( \
    (const __attribute__((address_space(1))) void*)(gp), \
    (__attribute__((address_space(3))) void*)(lp), 16, 0, 0)

__device__ __forceinline__ u16 f2bf(float f){
    unsigned u = __float_as_uint(f);
    u = u + 0x7FFFu + ((u >> 16) & 1u);   // RNE
    return (u16)(u >> 16);
}

__device__ __forceinline__ float tanh_fast(float x){
    float e = __builtin_amdgcn_exp2f(x * 2.885390082f);
    return 1.0f - 2.0f * __builtin_amdgcn_rcpf(e + 1.0f);
}

// ---------------- keys fp32 -> bf16 (linear) -------------------------------------
__global__ __launch_bounds__(256) void k_cvt(const float* __restrict__ in,
                                             u16* __restrict__ out){
    int gid = blockIdx.x * 256 + threadIdx.x;   // 4096 blocks -> 1048576 threads
#pragma unroll
    for (int i = 0; i < 4; ++i){
        size_t c = (size_t)i * 1048576 + gid;   // chunk of 16 floats
        const f32x4* ip = (const f32x4*)in + c * 4;
        f32x4 a0 = ip[0], a1 = ip[1], a2 = ip[2], a3 = ip[3];
        s16x8 o0, o1;
        o0[0]=f2bf(a0.x); o0[1]=f2bf(a0.y); o0[2]=f2bf(a0.z); o0[3]=f2bf(a0.w);
        o0[4]=f2bf(a1.x); o0[5]=f2bf(a1.y); o0[6]=f2bf(a1.z); o0[7]=f2bf(a1.w);
        o1[0]=f2bf(a2.x); o1[1]=f2bf(a2.y); o1[2]=f2bf(a2.z); o1[3]=f2bf(a2.w);
        o1[4]=f2bf(a3.x); o1[5]=f2bf(a3.y); o1[6]=f2bf(a3.z); o1[7]=f2bf(a3.w);
        ((s16x8*)out)[c * 2 + 0] = o0;
        ((s16x8*)out)[c * 2 + 1] = o1;
    }
}

// ---------------- W1 -> W1T (bf16, transposed) -----------------------------------
__global__ __launch_bounds__(256) void k_w1t(const float* __restrict__ W1,
                                             u16* __restrict__ W1T){
    __shared__ u16 t[64][65];
    int blk = blockIdx.x;
    int bh = blk >> 4, bd = blk & 15;
    int h0 = bh * 64, d0 = bd * 64;
    int tid = threadIdx.x;
    int lh = tid >> 4, ld = (tid & 15) * 4;
#pragma unroll
    for (int i = 0; i < 4; ++i){
        int hh = lh + i * 16;
        f32x4 v = *(const f32x4*)&W1[(size_t)(h0 + hh) * HDIM + d0 + ld];
        t[hh][ld + 0] = f2bf(v.x);
        t[hh][ld + 1] = f2bf(v.y);
        t[hh][ld + 2] = f2bf(v.z);
        t[hh][ld + 3] = f2bf(v.w);
    }
    __syncthreads();
    int wv = tid >> 6, ln = tid & 63;
#pragma unroll
    for (int i = 0; i < 16; ++i){
        int d = i * 4 + wv;
        W1T[(size_t)(d0 + d) * HDIM + h0 + ln] = t[ln][d];
    }
}

// ---------------- qproj[b][d] = sum_h query[b][h] * W2[h][d]  (fp32) -------------
__global__ __launch_bounds__(256) void k_qproj(const float* __restrict__ query,
                                               const float* __restrict__ W2,
                                               float* __restrict__ qproj){
    int blk = blockIdx.x;
    int b = blk >> 2, dc = blk & 3;
    int d = dc * 256 + threadIdx.x;
    const float* q = query + (size_t)b * HDIM;
    float acc = 0.f;
#pragma unroll 8
    for (int h = 0; h < HDIM; ++h)
        acc += q[h] * W2[(size_t)h * HDIM + d];
    qproj[(size_t)b * HDIM + d] = acc;
}

// ---------------- m97-style fused scores GEMM ------------------------------------
__global__ __launch_bounds__(256, 4) void k_score(const u16* __restrict__ keysbf,
                                                  const u16* __restrict__ W1T,
                                                  const float* __restrict__ qproj,
                                                  const float* __restrict__ V,
                                                  float* __restrict__ spart){
    // XCD swizzle: 4096 = 8 XCD * 512; 8 n-tiles of an m-tile stay on one XCD
    int bid  = blockIdx.x;
    int lid  = (bid & 7) * 512 + (bid >> 3);
    int mt   = lid >> 3;          // 0..511
    int nt   = lid & 7;           // 0..7

    __shared__ u16 As[2][BM * BK];   // 8 KB each buf, linear (gload_lds requires)
    __shared__ u16 Bs[2][BM * BK];

    int tid  = threadIdx.x;
    int wave = tid >> 6, lane = tid & 63;
    int wr = wave >> 1, wc = wave & 1;
    int g  = lane >> 4, q = lane & 15;

    // staging: wave w covers rows [w*32, w*32+32) in two 16-row calls;
    // lane l -> row +(l>>2), 16B col chunk (l&3)
    int r0 = wave * 32 + (lane >> 2);
    int c0 = (lane & 3) * 8;
    const u16* sA0 = keysbf + (size_t)(mt * BM + r0) * HDIM + c0;
    const u16* sA1 = sA0 + 16 * HDIM;
    const u16* sB0 = W1T + (size_t)(nt * BN + r0) * HDIM + c0;
    const u16* sB1 = sB0 + 16 * HDIM;
    int dst0 = (wave * 32) * BK;       // elem offset, uniform per wave
    int dst1 = dst0 + 16 * BK;

    f32x4 acc[4][4];
#pragma unroll
    for (int m = 0; m < 4; ++m)
#pragma unroll
        for (int n = 0; n < 4; ++n) acc[m][n] = 0.f;

    auto stage = [&](int buf, int kt){
        int ko = kt * BK;
        GLD16(sA0 + ko, &As[buf][dst0]);
        GLD16(sA1 + ko, &As[buf][dst1]);
        GLD16(sB0 + ko, &Bs[buf][dst0]);
        GLD16(sB1 + ko, &Bs[buf][dst1]);
    };

    stage(0, 0);
    __syncthreads();                   // drains prologue loads (vmcnt0 before barrier)
    int cur = 0;
    int abase = (wr * 64 + q) * BK + g * 8;
    int bbase = (wc * 64 + q) * BK + g * 8;

    for (int kt = 0; kt < NKT; ++kt){
        if (kt + 1 < NKT) stage(cur ^ 1, kt + 1);   // prefetch hides under MFMA
        s16x8 af[4], bq[4];
#pragma unroll
        for (int m = 0; m < 4; ++m) af[m] = *(const s16x8*)&As[cur][abase + m * 16 * BK];
#pragma unroll
        for (int n = 0; n < 4; ++n) bq[n] = *(const s16x8*)&Bs[cur][bbase + n * 16 * BK];
#pragma unroll
        for (int m = 0; m < 4; ++m)
#pragma unroll
            for (int n = 0; n < 4; ++n)
                acc[m][n] = __builtin_amdgcn_mfma_f32_16x16x32_bf16(af[m], bq[n], acc[m][n], 0, 0, 0);
        __syncthreads();               // one vmcnt(0)+barrier per K-tile
        cur ^= 1;
    }

    // epilogue: score partial = sum_d V[d]*tanh(proj + qproj[b][d]) over 64 cols
    int b_idx = mt >> 4;
    float Vn[4], Qn[4];
#pragma unroll
    for (int n = 0; n < 4; ++n){
        int D = nt * BN + wc * 64 + n * 16 + q;
        Vn[n] = V[D];
        Qn[n] = qproj[(size_t)b_idx * HDIM + D];
    }
#pragma unroll
    for (int m = 0; m < 4; ++m){
#pragma unroll
        for (int r = 0; r < 4; ++r){
            float s = 0.f;
#pragma unroll
            for (int n = 0; n < 4; ++n){
                float x = acc[m][n][r] + Qn[n];
                s += Vn[n] * tanh_fast(x);
            }
            s += __shfl_xor(s, 1);
            s += __shfl_xor(s, 2);
            s += __shfl_xor(s, 4);
            s += __shfl_xor(s, 8);
            if (q == 0){
                int R = mt * BM + wr * 64 + m * 16 + g * 4 + r;
                spart[(size_t)R * 16 + nt * 2 + wc] = s;
            }
        }
    }
}

// ---------------- fallback fused kernel (round-1, used if ws too small) ----------
#define LDK 40
__global__ __launch_bounds__(256, 2) void k_score_fused(const float* __restrict__ keys,
                                                  const u16*  __restrict__ W1T,
                                                  const float* __restrict__ qproj,
                                                  const float* __restrict__ V,
                                                  float* __restrict__ spart){
    int bid  = blockIdx.x;
    int lid  = (bid & 7) * 512 + (bid >> 3);
    int mt   = lid >> 3;
    int nt   = lid & 7;

    __shared__ u16 As[2][BM * LDK];
    __shared__ u16 Bs[2][BM * LDK];

    int tid  = threadIdx.x;
    int wave = tid >> 6, lane = tid & 63;
    int wr = wave >> 1, wc = wave & 1;
    int g  = lane >> 4, q = lane & 15;

    int srow = tid >> 1;
    int scol = (tid & 1) * 16;
    const float* Aptr = keys + (size_t)(mt * BM + srow) * HDIM + scol;
    const u16*   Bptr = W1T  + (size_t)(nt * BN + srow) * HDIM + scol;

    f32x4 ar[4];
    s16x8 br[2];
    f32x4 acc[4][4];
#pragma unroll
    for (int m = 0; m < 4; ++m)
#pragma unroll
        for (int n = 0; n < 4; ++n) acc[m][n] = 0.f;

    auto load_tile = [&](int kt){
        const float* ap = Aptr + kt * BK;
        ar[0] = *(const f32x4*)(ap + 0);
        ar[1] = *(const f32x4*)(ap + 4);
        ar[2] = *(const f32x4*)(ap + 8);
        ar[3] = *(const f32x4*)(ap + 12);
        const u16* bp = Bptr + kt * BK;
        br[0] = *(const s16x8*)(bp + 0);
        br[1] = *(const s16x8*)(bp + 8);
    };
    auto store_tile = [&](int buf){
        s16x8 p0, p1;
        p0[0]=f2bf(ar[0].x); p0[1]=f2bf(ar[0].y); p0[2]=f2bf(ar[0].z); p0[3]=f2bf(ar[0].w);
        p0[4]=f2bf(ar[1].x); p0[5]=f2bf(ar[1].y); p0[6]=f2bf(ar[1].z); p0[7]=f2bf(ar[1].w);
        p1[0]=f2bf(ar[2].x); p1[1]=f2bf(ar[2].y); p1[2]=f2bf(ar[2].z); p1[3]=f2bf(ar[2].w);
        p1[4]=f2bf(ar[3].x); p1[5]=f2bf(ar[3].y); p1[6]=f2bf(ar[3].z); p1[7]=f2bf(ar[3].w);
        int o = srow * LDK + scol;
        *(s16x8*)&As[buf][o + 0] = p0;
        *(s16x8*)&As[buf][o + 8] = p1;
        *(s16x8*)&Bs[buf][o + 0] = br[0];
        *(s16x8*)&Bs[buf][o + 8] = br[1];
    };

    load_tile(0);
    store_tile(0);
    int cur = 0;
    int abase = (wr * 64 + q) * LDK + g * 8;
    int bbase = (wc * 64 + q) * LDK + g * 8;

    for (int kt = 0; kt < NKT; ++kt){
        if (kt + 1 < NKT) load_tile(kt + 1);
        __syncthreads();
        s16x8 af[4], bq[4];
#pragma unroll
        for (int m = 0; m < 4; ++m) af[m] = *(const s16x8*)&As[cur][abase + m * 16 * LDK];
#pragma unroll
        for (int n = 0; n < 4; ++n) bq[n] = *(const s16x8*)&Bs[cur][bbase + n * 16 * LDK];
#pragma unroll
        for (int m = 0; m < 4; ++m)
#pragma unroll
            for (int n = 0; n < 4; ++n)
                acc[m][n] = __builtin_amdgcn_mfma_f32_16x16x32_bf16(af[m], bq[n], acc[m][n], 0, 0, 0);
        if (kt + 1 < NKT) store_tile(cur ^ 1);
        cur ^= 1;
    }

    int b_idx = mt >> 4;
    float Vn[4], Qn[4];
#pragma unroll
    for (int n = 0; n < 4; ++n){
        int D = nt * BN + wc * 64 + n * 16 + q;
        Vn[n] = V[D];
        Qn[n] = qproj[(size_t)b_idx * HDIM + D];
    }
#pragma unroll
    for (int m = 0; m < 4; ++m){
#pragma unroll
        for (int r = 0; r < 4; ++r){
            float s = 0.f;
#pragma unroll
            for (int n = 0; n < 4; ++n){
                float x = acc[m][n][r] + Qn[n];
                s += Vn[n] * tanh_fast(x);
            }
            s += __shfl_xor(s, 1);
            s += __shfl_xor(s, 2);
            s += __shfl_xor(s, 4);
            s += __shfl_xor(s, 8);
            if (q == 0){
                int R = mt * BM + wr * 64 + m * 16 + g * 4 + r;
                spart[(size_t)R * 16 + nt * 2 + wc] = s;
            }
        }
    }
}

// ---------------- softmax over S per batch ---------------------------------------
__global__ __launch_bounds__(256) void k_softmax(const float* __restrict__ spart,
                                                 const int* __restrict__ mask,
                                                 float* __restrict__ attn){
    int b = blockIdx.x;
    int tid = threadIdx.x;
    int lane = tid & 63, wv = tid >> 6;
    __shared__ float redmx[4];
    __shared__ float redsm[4];

    float sc[8];
#pragma unroll
    for (int i = 0; i < 8; ++i){
        int s = i * 256 + tid;
        const f32x4* p = (const f32x4*)&spart[(size_t)(b * SEQ + s) * 16];
        f32x4 v0 = p[0], v1 = p[1], v2 = p[2], v3 = p[3];
        float sum = (v0.x + v0.y + v0.z + v0.w) + (v1.x + v1.y + v1.z + v1.w)
                  + (v2.x + v2.y + v2.z + v2.w) + (v3.x + v3.y + v3.z + v3.w);
        sc[i] = (mask[b * SEQ + s] == 0) ? -1e9f : sum;
    }
    float mx = sc[0];
#pragma unroll
    for (int i = 1; i < 8; ++i) mx = fmaxf(mx, sc[i]);
#pragma unroll
    for (int o = 32; o >= 1; o >>= 1) mx = fmaxf(mx, __shfl_xor(mx, o));
    if (lane == 0) redmx[wv] = mx;
    __syncthreads();
    mx = fmaxf(fmaxf(redmx[0], redmx[1]), fmaxf(redmx[2], redmx[3]));

    float ex[8], ssum = 0.f;
#pragma unroll
    for (int i = 0; i < 8; ++i){
        ex[i] = __builtin_amdgcn_exp2f((sc[i] - mx) * 1.4426950408889634f);
        ssum += ex[i];
    }
#pragma unroll
    for (int o = 32; o >= 1; o >>= 1) ssum += __shfl_xor(ssum, o);
    if (lane == 0) redsm[wv] = ssum;
    __syncthreads();
    ssum = redsm[0] + redsm[1] + redsm[2] + redsm[3];
    float inv = 1.0f / ssum;
#pragma unroll
    for (int i = 0; i < 8; ++i)
        attn[(size_t)b * SEQ + i * 256 + tid] = ex[i] * inv;
}

// ---------------- context partials: cpart[b][sc][h] ------------------------------
__global__ __launch_bounds__(256) void k_ctxpart(const float* __restrict__ keys,
                                                 const float* __restrict__ attn,
                                                 float* __restrict__ cpart){
    int blk = blockIdx.x;
    int b = blk >> 4, scn = blk & 15;
    int tid = threadIdx.x;
    f32x4 acc = 0.f;
    const f32x4* kp = (const f32x4*)(keys + (size_t)(b * SEQ + scn * 128) * HDIM) + tid;
    const float* ap = attn + (size_t)b * SEQ + scn * 128;
#pragma unroll 4
    for (int s = 0; s < 128; ++s){
        float a = ap[s];
        acc += a * kp[(size_t)s * 256];
    }
    *(f32x4*)&cpart[(size_t)(b * 16 + scn) * HDIM + tid * 4] = acc;
}

__global__ __launch_bounds__(256) void k_ctxred(const float* __restrict__ cpart,
                                                float* __restrict__ ctx){
    int idx = blockIdx.x * 256 + threadIdx.x;
    int b = idx >> 10, h = idx & 1023;
    float s = 0.f;
#pragma unroll
    for (int sc = 0; sc < 16; ++sc)
        s += cpart[(size_t)(b * 16 + sc) * HDIM + h];
    ctx[idx] = s;
}

// ---------------- launch ---------------------------------------------------------
extern "C" void kernel_launch(void* const* d_in, const int* in_sizes, int n_in,
                              void* d_out, int out_size, void* d_ws, size_t ws_size,
                              hipStream_t stream){
    (void)in_sizes; (void)n_in; (void)out_size;
    const float* query = (const float*)d_in[0];
    const float* keys  = (const float*)d_in[1];
    const int*   mask  = (const int*)d_in[2];
    const float* W1    = (const float*)d_in[3];
    const float* W2    = (const float*)d_in[4];
    const float* V     = (const float*)d_in[5];

    float* ctx_out  = (float*)d_out;            // [32][1024]
    float* attn_out = ctx_out + BATCH * HDIM;   // [32][2048]

    char* ws = (char*)d_ws;
    u16*   W1T   = (u16*)ws;                                   // 2 MB
    float* qproj = (float*)(ws + (2u << 20));                  // 128 KB
    float* spart = (float*)(ws + (2u << 20) + (128u << 10));   // 4 MB
    float* cpart = (float*)(ws + (6u << 20) + (128u << 10));   // 2 MB
    u16*   keysbf= (u16*)(ws + (9u << 20));                    // 128 MB

    const size_t need = (9u << 20) + (size_t)NROWS * HDIM * sizeof(u16);

    k_w1t    <<<dim3(256),  dim3(256), 0, stream>>>(W1, W1T);
    k_qproj  <<<dim3(128),  dim3(256), 0, stream>>>(query, W2, qproj);
    if (ws_size >= need){
        k_cvt  <<<dim3(4096), dim3(256), 0, stream>>>(keys, keysbf);
        k_score<<<dim3(4096), dim3(256), 0, stream>>>(keysbf, W1T, qproj, V, spart);
    } else {
        k_score_fused<<<dim3(4096), dim3(256), 0, stream>>>(keys, W1T, qproj, V, spart);
    }
    k_softmax<<<dim3(32),   dim3(256), 0, stream>>>(spart, mask, attn_out);
    k_ctxpart<<<dim3(512),  dim3(256), 0, stream>>>(keys, attn_out, cpart);
    k_ctxred <<<dim3(128),  dim3(256), 0, stream>>>(cpart, ctx_out);
}

// Round 3
// 350.155 us; speedup vs baseline: 1.0326x; 1.0326x over previous
//
#include <hip/hip_runtime.h>

typedef float  f32x4 __attribute__((ext_vector_type(4)));
typedef short  s16x8 __attribute__((ext_vector_type(8)));
typedef short  s16x4 __attribute__((ext_vector_type(4)));
typedef unsigned short u16;

#define HDIM 1024
#define BATCH 32
#define SEQ 2048
#define NROWS (BATCH*SEQ)   // 65536

// 256x256 tile, BK=32, 8 waves (2M x 4N), 512 threads
#define BM 256
#define BN 256
#define BK 32
#define NKT (HDIM/BK)       // 32

#define GLD16(gp, lp) __builtin_amdgcn_global_load_lds( \
    (const __attribute__((address_space(1))) void*)(gp), \
    (__attribute__((address_space(3))) void*)(lp), 16, 0, 0)

#define VMCNT(n) asm volatile("s_waitcnt vmcnt(" #n ")" ::: "memory")
#define LGKMCNT0 asm volatile("s_waitcnt lgkmcnt(0)" ::: "memory")
#define SCHEDB __builtin_amdgcn_sched_barrier(0)

__device__ __forceinline__ u16 f2bf(float f){
    unsigned u = __float_as_uint(f);
    u = u + 0x7FFFu + ((u >> 16) & 1u);   // RNE
    return (u16)(u >> 16);
}

__device__ __forceinline__ float tanh_fast(float x){
    float e = __builtin_amdgcn_exp2f(x * 2.885390082f);
    return 1.0f - 2.0f * __builtin_amdgcn_rcpf(e + 1.0f);
}

// ---------------- keys fp32 -> bf16, fully coalesced -----------------------------
// lane reads one contiguous f32x4 (16B), writes s16x4 (8B); grid-stride.
__global__ __launch_bounds__(256) void k_cvt(const float* __restrict__ in,
                                             u16* __restrict__ out){
    size_t base = (size_t)blockIdx.x * 256 + threadIdx.x;   // 2048*256 = 524288 threads
    const f32x4* ip = (const f32x4*)in;
    s16x4* op = (s16x4*)out;
#pragma unroll 4
    for (int i = 0; i < 32; ++i){
        size_t c = base + (size_t)i * 524288;               // 16,777,216 chunks total
        f32x4 v = ip[c];
        s16x4 o;
        o[0] = (short)f2bf(v.x); o[1] = (short)f2bf(v.y);
        o[2] = (short)f2bf(v.z); o[3] = (short)f2bf(v.w);
        op[c] = o;
    }
}

// ---------------- W1 -> W1T (bf16, transposed) -----------------------------------
__global__ __launch_bounds__(256) void k_w1t(const float* __restrict__ W1,
                                             u16* __restrict__ W1T){
    __shared__ u16 t[64][65];
    int blk = blockIdx.x;
    int bh = blk >> 4, bd = blk & 15;
    int h0 = bh * 64, d0 = bd * 64;
    int tid = threadIdx.x;
    int lh = tid >> 4, ld = (tid & 15) * 4;
#pragma unroll
    for (int i = 0; i < 4; ++i){
        int hh = lh + i * 16;
        f32x4 v = *(const f32x4*)&W1[(size_t)(h0 + hh) * HDIM + d0 + ld];
        t[hh][ld + 0] = f2bf(v.x);
        t[hh][ld + 1] = f2bf(v.y);
        t[hh][ld + 2] = f2bf(v.z);
        t[hh][ld + 3] = f2bf(v.w);
    }
    __syncthreads();
    int wv = tid >> 6, ln = tid & 63;
#pragma unroll
    for (int i = 0; i < 16; ++i){
        int d = i * 4 + wv;
        W1T[(size_t)(d0 + d) * HDIM + h0 + ln] = t[ln][d];
    }
}

// ---------------- qproj[b][d] = sum_h query[b][h] * W2[h][d]  (fp32) -------------
__global__ __launch_bounds__(256) void k_qproj(const float* __restrict__ query,
                                               const float* __restrict__ W2,
                                               float* __restrict__ qproj){
    int blk = blockIdx.x;
    int b = blk >> 2, dc = blk & 3;
    int d = dc * 256 + threadIdx.x;
    const float* q = query + (size_t)b * HDIM;
    float acc = 0.f;
#pragma unroll 8
    for (int h = 0; h < HDIM; ++h)
        acc += q[h] * W2[(size_t)h * HDIM + d];
    qproj[(size_t)b * HDIM + d] = acc;
}

// ---------------- 256^2-tile counted-vmcnt scores GEMM ---------------------------
// 8 waves (wm 0..1, wn 0..3); per-wave output 128x64 (8m x 4n frags of 16x16).
// LDS: 2 bufs x (A 256x32 + B 256x32) bf16 = 64 KB. T2 swizzle: slot ^= (row>>1)&3,
// applied on the GLOBAL source (gload_lds dest stays linear) and on the LDS read.
__global__ __launch_bounds__(512, 2) void k_score(const u16* __restrict__ keysbf,
                                                  const u16* __restrict__ W1T,
                                                  const float* __restrict__ qproj,
                                                  const float* __restrict__ V,
                                                  float* __restrict__ spart){
    // XCD swizzle: 1024 blocks = 8 XCD * 128; 4 n-tiles of an m-tile on one XCD
    int bid = blockIdx.x;
    int lid = (bid & 7) * 128 + (bid >> 3);
    int mt  = lid >> 2;           // 0..255
    int nt  = lid & 3;            // 0..3

    __shared__ u16 As[2][BM * BK];   // 16 KB per buf
    __shared__ u16 Bs[2][BM * BK];

    int tid  = threadIdx.x;
    int lane = tid & 63;
    int wave = tid >> 6;
    int wm = wave >> 2, wn = wave & 3;
    int g  = lane >> 4, q = lane & 15;

    // ---- staging addresses (pre-swizzled global source, linear LDS dest) ----
    int srow = tid >> 2;                          // 0..127
    int schunk = (tid & 3) ^ ((tid >> 3) & 3);    // XOR'd 16B chunk within 64B row
    int scol = schunk * 8;                        // elems
    const u16* asrc = keysbf + (size_t)(mt * BM + srow) * HDIM + scol;
    const u16* bsrc = W1T    + (size_t)(nt * BN + srow) * HDIM + scol;
    int dst = tid * 8;                            // elem offset = lane*16B + wave*1KB

    auto stage = [&](int buf, int kt){
        int ko = kt * BK;
        GLD16(asrc + ko,               &As[buf][dst]);
        GLD16(asrc + ko + 128 * HDIM,  &As[buf][dst + 128 * BK]);
        GLD16(bsrc + ko,               &Bs[buf][dst]);
        GLD16(bsrc + ko + 128 * HDIM,  &Bs[buf][dst + 128 * BK]);
    };

    // ---- read offsets (swizzled) ----
    int slotx = (q >> 1) & 3;
    int rslot = (g ^ slotx) * 8;                  // lane-constant
    int aoff = (wm * 128 + q) * BK + rslot;       // + m*16*BK per m-frag
    int boff = (wn * 64 + q) * BK + rslot;        // + n*16*BK per n-frag

    f32x4 acc[8][4];
#pragma unroll
    for (int m = 0; m < 8; ++m)
#pragma unroll
        for (int n = 0; n < 4; ++n) acc[m][n] = 0.f;

    // ---- prologue: stage kt0, kt1; wait kt0 landed ----
    stage(0, 0);
    stage(1, 1);
    VMCNT(4);
    SCHEDB;
    __builtin_amdgcn_s_barrier();
    SCHEDB;

    for (int kt = 0; kt < NKT; ++kt){
        int cur = kt & 1;
        s16x8 af[8], bq[4];
#pragma unroll
        for (int m = 0; m < 8; ++m) af[m] = *(const s16x8*)&As[cur][aoff + m * 16 * BK];
#pragma unroll
        for (int n = 0; n < 4; ++n) bq[n] = *(const s16x8*)&Bs[cur][boff + n * 16 * BK];

        __builtin_amdgcn_s_setprio(1);
#pragma unroll
        for (int m = 0; m < 8; ++m)
#pragma unroll
            for (int n = 0; n < 4; ++n)
                acc[m][n] = __builtin_amdgcn_mfma_f32_16x16x32_bf16(af[m], bq[n], acc[m][n], 0, 0, 0);
        __builtin_amdgcn_s_setprio(0);

        SCHEDB;
        LGKMCNT0;                       // this wave's ds_reads of buf cur complete
        __builtin_amdgcn_s_barrier();   // all waves done reading buf cur
        SCHEDB;
        // stage kt+2 into buf cur (dummy re-stage at tail keeps vmcnt uniform;
        // dummy target buf is never read again)
        stage(cur, (kt + 2 < NKT) ? kt + 2 : NKT - 1);
        VMCNT(4);                       // tile kt+1 (issued last iter) fully landed
        SCHEDB;
        __builtin_amdgcn_s_barrier();   // all waves agree buf cur^1 is ready
        SCHEDB;
    }
    VMCNT(0);   // drain dummy stages: LDS writes must not land after block retires

    // ---- epilogue: spart[R][nt*4+wn] = sum over this wave's 64 d-cols ----
    int b_idx = mt >> 3;                // 8 m-tiles per batch
    float Vn[4], Qn[4];
#pragma unroll
    for (int n = 0; n < 4; ++n){
        int D = nt * BN + wn * 64 + n * 16 + q;
        Vn[n] = V[D];
        Qn[n] = qproj[(size_t)b_idx * HDIM + D];
    }
#pragma unroll
    for (int m = 0; m < 8; ++m){
#pragma unroll
        for (int r = 0; r < 4; ++r){
            float s = 0.f;
#pragma unroll
            for (int n = 0; n < 4; ++n){
                float x = acc[m][n][r] + Qn[n];
                s += Vn[n] * tanh_fast(x);
            }
            s += __shfl_xor(s, 1);
            s += __shfl_xor(s, 2);
            s += __shfl_xor(s, 4);
            s += __shfl_xor(s, 8);
            if (q == 0){
                int R = mt * BM + wm * 128 + m * 16 + g * 4 + r;
                spart[(size_t)R * 16 + nt * 4 + wn] = s;
            }
        }
    }
}

// ---------------- softmax over S per batch ---------------------------------------
__global__ __launch_bounds__(256) void k_softmax(const float* __restrict__ spart,
                                                 const int* __restrict__ mask,
                                                 float* __restrict__ attn){
    int b = blockIdx.x;
    int tid = threadIdx.x;
    int lane = tid & 63, wv = tid >> 6;
    __shared__ float redmx[4];
    __shared__ float redsm[4];

    float sc[8];
#pragma unroll
    for (int i = 0; i < 8; ++i){
        int s = i * 256 + tid;
        const f32x4* p = (const f32x4*)&spart[(size_t)(b * SEQ + s) * 16];
        f32x4 v0 = p[0], v1 = p[1], v2 = p[2], v3 = p[3];
        float sum = (v0.x + v0.y + v0.z + v0.w) + (v1.x + v1.y + v1.z + v1.w)
                  + (v2.x + v2.y + v2.z + v2.w) + (v3.x + v3.y + v3.z + v3.w);
        sc[i] = (mask[b * SEQ + s] == 0) ? -1e9f : sum;
    }
    float mx = sc[0];
#pragma unroll
    for (int i = 1; i < 8; ++i) mx = fmaxf(mx, sc[i]);
#pragma unroll
    for (int o = 32; o >= 1; o >>= 1) mx = fmaxf(mx, __shfl_xor(mx, o));
    if (lane == 0) redmx[wv] = mx;
    __syncthreads();
    mx = fmaxf(fmaxf(redmx[0], redmx[1]), fmaxf(redmx[2], redmx[3]));

    float ex[8], ssum = 0.f;
#pragma unroll
    for (int i = 0; i < 8; ++i){
        ex[i] = __builtin_amdgcn_exp2f((sc[i] - mx) * 1.4426950408889634f);
        ssum += ex[i];
    }
#pragma unroll
    for (int o = 32; o >= 1; o >>= 1) ssum += __shfl_xor(ssum, o);
    if (lane == 0) redsm[wv] = ssum;
    __syncthreads();
    ssum = redsm[0] + redsm[1] + redsm[2] + redsm[3];
    float inv = 1.0f / ssum;
#pragma unroll
    for (int i = 0; i < 8; ++i)
        attn[(size_t)b * SEQ + i * 256 + tid] = ex[i] * inv;
}

// ---------------- context partials: cpart[b][sc][h] ------------------------------
__global__ __launch_bounds__(256) void k_ctxpart(const float* __restrict__ keys,
                                                 const float* __restrict__ attn,
                                                 float* __restrict__ cpart){
    int blk = blockIdx.x;
    int b = blk >> 4, scn = blk & 15;
    int tid = threadIdx.x;
    f32x4 acc = 0.f;
    const f32x4* kp = (const f32x4*)(keys + (size_t)(b * SEQ + scn * 128) * HDIM) + tid;
    const float* ap = attn + (size_t)b * SEQ + scn * 128;
#pragma unroll 4
    for (int s = 0; s < 128; ++s){
        float a = ap[s];
        acc += a * kp[(size_t)s * 256];
    }
    *(f32x4*)&cpart[(size_t)(b * 16 + scn) * HDIM + tid * 4] = acc;
}

__global__ __launch_bounds__(256) void k_ctxred(const float* __restrict__ cpart,
                                                float* __restrict__ ctx){
    int idx = blockIdx.x * 256 + threadIdx.x;
    int b = idx >> 10, h = idx & 1023;
    float s = 0.f;
#pragma unroll
    for (int sc = 0; sc < 16; ++sc)
        s += cpart[(size_t)(b * 16 + sc) * HDIM + h];
    ctx[idx] = s;
}

// ---------------- launch ---------------------------------------------------------
extern "C" void kernel_launch(void* const* d_in, const int* in_sizes, int n_in,
                              void* d_out, int out_size, void* d_ws, size_t ws_size,
                              hipStream_t stream){
    (void)in_sizes; (void)n_in; (void)out_size; (void)ws_size;
    const float* query = (const float*)d_in[0];
    const float* keys  = (const float*)d_in[1];
    const int*   mask  = (const int*)d_in[2];
    const float* W1    = (const float*)d_in[3];
    const float* W2    = (const float*)d_in[4];
    const float* V     = (const float*)d_in[5];

    float* ctx_out  = (float*)d_out;            // [32][1024]
    float* attn_out = ctx_out + BATCH * HDIM;   // [32][2048]

    char* ws = (char*)d_ws;
    u16*   W1T   = (u16*)ws;                                   // 2 MB
    float* qproj = (float*)(ws + (2u << 20));                  // 128 KB
    float* spart = (float*)(ws + (2u << 20) + (128u << 10));   // 4 MB
    float* cpart = (float*)(ws + (6u << 20) + (128u << 10));   // 2 MB
    u16*   keysbf= (u16*)(ws + (9u << 20));                    // 128 MB

    k_w1t    <<<dim3(256),  dim3(256), 0, stream>>>(W1, W1T);
    k_qproj  <<<dim3(128),  dim3(256), 0, stream>>>(query, W2, qproj);
    k_cvt    <<<dim3(2048), dim3(256), 0, stream>>>(keys, keysbf);
    k_score  <<<dim3(1024), dim3(512), 0, stream>>>(keysbf, W1T, qproj, V, spart);
    k_softmax<<<dim3(32),   dim3(256), 0, stream>>>(spart, mask, attn_out);
    k_ctxpart<<<dim3(512),  dim3(256), 0, stream>>>(keys, attn_out, cpart);
    k_ctxred <<<dim3(128),  dim3(256), 0, stream>>>(cpart, ctx_out);
}

// Round 4
// 298.065 us; speedup vs baseline: 1.2130x; 1.1748x over previous
//
#include <hip/hip_runtime.h>

typedef float  f32x4 __attribute__((ext_vector_type(4)));
typedef short  s16x8 __attribute__((ext_vector_type(8)));
typedef short  s16x4 __attribute__((ext_vector_type(4)));
typedef unsigned short u16;

#define HDIM 1024
#define BATCH 32
#define SEQ 2048
#define NROWS (BATCH*SEQ)   // 65536

// k_score geometry: 256x256 tile, BK=64, 8 waves (2M x 4N), 512 threads, 1 blk/CU
#define NTILES 16           // K / 64
#define PLANE 4096          // elems per LDS plane: 128 rows x 32 (64B rows)

#define GLD16(gp, lp) __builtin_amdgcn_global_load_lds( \
    (const __attribute__((address_space(1))) void*)(gp), \
    (__attribute__((address_space(3))) void*)(lp), 16, 0, 0)

#define VMCNT(n) asm volatile("s_waitcnt vmcnt(" #n ")" ::: "memory")
#define LGKMCNT0 asm volatile("s_waitcnt lgkmcnt(0)" ::: "memory")
#define SCHEDB __builtin_amdgcn_sched_barrier(0)

__device__ __forceinline__ u16 f2bf(float f){
    unsigned u = __float_as_uint(f);
    u = u + 0x7FFFu + ((u >> 16) & 1u);   // RNE
    return (u16)(u >> 16);
}

__device__ __forceinline__ float tanh_fast(float x){
    float e = __builtin_amdgcn_exp2f(x * 2.885390082f);
    return 1.0f - 2.0f * __builtin_amdgcn_rcpf(e + 1.0f);
}

// ---------------- keys fp32 -> bf16, coalesced -----------------------------------
__global__ __launch_bounds__(256) void k_cvt(const float* __restrict__ in,
                                             u16* __restrict__ out){
    size_t base = (size_t)blockIdx.x * 256 + threadIdx.x;   // 524288 threads
    const f32x4* ip = (const f32x4*)in;
    s16x4* op = (s16x4*)out;
#pragma unroll 4
    for (int i = 0; i < 32; ++i){
        size_t c = base + (size_t)i * 524288;
        f32x4 v = ip[c];
        s16x4 o;
        o[0] = (short)f2bf(v.x); o[1] = (short)f2bf(v.y);
        o[2] = (short)f2bf(v.z); o[3] = (short)f2bf(v.w);
        op[c] = o;
    }
}

// ---------------- W1 -> W1T (bf16, transposed) -----------------------------------
__global__ __launch_bounds__(256) void k_w1t(const float* __restrict__ W1,
                                             u16* __restrict__ W1T){
    __shared__ u16 t[64][65];
    int blk = blockIdx.x;
    int bh = blk >> 4, bd = blk & 15;
    int h0 = bh * 64, d0 = bd * 64;
    int tid = threadIdx.x;
    int lh = tid >> 4, ld = (tid & 15) * 4;
#pragma unroll
    for (int i = 0; i < 4; ++i){
        int hh = lh + i * 16;
        f32x4 v = *(const f32x4*)&W1[(size_t)(h0 + hh) * HDIM + d0 + ld];
        t[hh][ld + 0] = f2bf(v.x);
        t[hh][ld + 1] = f2bf(v.y);
        t[hh][ld + 2] = f2bf(v.z);
        t[hh][ld + 3] = f2bf(v.w);
    }
    __syncthreads();
    int wv = tid >> 6, ln = tid & 63;
#pragma unroll
    for (int i = 0; i < 16; ++i){
        int d = i * 4 + wv;
        W1T[(size_t)(d0 + d) * HDIM + h0 + ln] = t[ln][d];
    }
}

// ---------------- qproj: 512 blocks, 4 h-quarter partials + LDS reduce -----------
__global__ __launch_bounds__(256) void k_qproj(const float* __restrict__ query,
                                               const float* __restrict__ W2,
                                               float* __restrict__ qproj){
    int b = blockIdx.x >> 4, dc = blockIdx.x & 15;
    int t = threadIdx.x;
    int dl = t & 63, hq = t >> 6;
    int d = dc * 64 + dl;
    const float* q = query + (size_t)b * HDIM;
    float acc = 0.f;
#pragma unroll 8
    for (int h = hq * 256; h < hq * 256 + 256; ++h)
        acc += q[h] * W2[(size_t)h * HDIM + d];
    __shared__ float red[4][64];
    red[hq][dl] = acc;
    __syncthreads();
    if (hq == 0)
        qproj[(size_t)b * HDIM + d] = red[0][dl] + red[1][dl] + red[2][dl] + red[3][dl];
}

// ---------------- 8-phase 256^2 scores GEMM --------------------------------------
// LDS planes: [buf(2)][half(2)][ks(2)] of 128 rows x 32 elems (64B rows).
// Swizzle (proven 0-conflict): LDS[r][slot] = G[r][slot ^ ((r>>1)&3)] per plane.
// Unit pipeline: U(t,0)=A-ks0, U(t,1)=B-ks0, U(t,2)=A-ks1, U(t,3)=B-ks1; one unit
// (2 gload_lds) issued per phase; each unit lands >=4 phases before consumption;
// VMCNT(4)+barrier at tile start (U0,U1) and mid-tile (U2,U3). Never vmcnt(0) in-loop.
__global__ __launch_bounds__(512, 2) void k_score(const u16* __restrict__ keysbf,
                                                  const u16* __restrict__ W1T,
                                                  const float* __restrict__ qproj,
                                                  const float* __restrict__ V,
                                                  float* __restrict__ spart){
    int bid = blockIdx.x;
    int lid = (bid & 7) * 128 + (bid >> 3);   // XCD swizzle; 4 nt of one mt per XCD
    int mt  = lid >> 2;           // 0..255
    int nt  = lid & 3;            // 0..3

    __shared__ u16 As[8 * PLANE];   // 64 KB
    __shared__ u16 Bs[8 * PLANE];   // 64 KB

    int tid  = threadIdx.x;
    int lane = tid & 63, wave = tid >> 6;
    int wm = wave >> 2, wn = wave & 3;
    int g  = lane >> 4, q = lane & 15;

    // staging coords
    int sr = tid >> 2, sl = tid & 3;
    int ch = sl ^ ((sr >> 1) & 3);            // pre-swizzled global 16B chunk
    const u16* abase = keysbf + (size_t)(mt * 256 + sr) * HDIM + ch * 8;
    const u16* bbase = W1T    + (size_t)(nt * 256 + sr) * HDIM + ch * 8;
    int sdst = tid * 8;                       // lane*16B within plane

    auto stageA = [&](int buf, int t, int ks){
        int ko = t * 64 + ks * 32;
        GLD16(abase + ko,              &As[((buf << 2) | ks) * PLANE + sdst]);
        GLD16(abase + ko + 128 * HDIM, &As[((buf << 2) | 2 | ks) * PLANE + sdst]);
    };
    auto stageB = [&](int buf, int t, int ks){
        int ko = t * 64 + ks * 32;
        GLD16(bbase + ko,              &Bs[((buf << 2) | ks) * PLANE + sdst]);
        GLD16(bbase + ko + 128 * HDIM, &Bs[((buf << 2) | 2 | ks) * PLANE + sdst]);
    };

    // read offsets (swizzled, lane-constant across frags)
    int rslot = (g ^ ((q >> 1) & 3)) * 8;
    int arow  = q * 32 + rslot;                        // + m*512
    int brow  = ((wn & 1) * 64 + q) * 32 + rslot;      // + n*512

    f32x4 acc[8][4];
#pragma unroll
    for (int m = 0; m < 8; ++m)
#pragma unroll
        for (int n = 0; n < 4; ++n) acc[m][n] = 0.f;

    // prologue: tile 0, all 4 units (8 loads)
    stageA(0, 0, 0); stageB(0, 0, 0); stageA(0, 0, 1); stageB(0, 0, 1);

    for (int t = 0; t < NTILES; ++t){
        int c = t & 1, nb = c ^ 1;
        int tn = (t < NTILES - 1) ? t + 1 : NTILES - 1;   // dummy re-stage at tail
        s16x8 af[4], bq[4];
        const u16* Ap = &As[((c << 2) | (wm << 1)) * PLANE];
        const u16* Bp = &Bs[((c << 2) | (wn >> 1 << 1)) * PLANE];

        VMCNT(4); SCHEDB;                    // U(t,0),U(t,1) landed (oldest 4 loads)
        __builtin_amdgcn_s_barrier(); SCHEDB;

        // ---- P0: m0-3 x ks0 ----
#pragma unroll
        for (int m = 0; m < 4; ++m) af[m] = *(const s16x8*)&Ap[arow + m * 512];
#pragma unroll
        for (int n = 0; n < 4; ++n) bq[n] = *(const s16x8*)&Bp[brow + n * 512];
        stageA(nb, tn, 0);
        LGKMCNT0; SCHEDB;
        __builtin_amdgcn_s_setprio(1);
#pragma unroll
        for (int m = 0; m < 4; ++m)
#pragma unroll
            for (int n = 0; n < 4; ++n)
                acc[m][n] = __builtin_amdgcn_mfma_f32_16x16x32_bf16(af[m], bq[n], acc[m][n], 0, 0, 0);
        __builtin_amdgcn_s_setprio(0); SCHEDB;
        __builtin_amdgcn_s_barrier();

        // ---- P1: m4-7 x ks0 (bq reused) ----
#pragma unroll
        for (int m = 0; m < 4; ++m) af[m] = *(const s16x8*)&Ap[arow + (m + 4) * 512];
        stageB(nb, tn, 0);
        LGKMCNT0; SCHEDB;
        __builtin_amdgcn_s_setprio(1);
#pragma unroll
        for (int m = 0; m < 4; ++m)
#pragma unroll
            for (int n = 0; n < 4; ++n)
                acc[m + 4][n] = __builtin_amdgcn_mfma_f32_16x16x32_bf16(af[m], bq[n], acc[m + 4][n], 0, 0, 0);
        __builtin_amdgcn_s_setprio(0); SCHEDB;

        VMCNT(4); SCHEDB;                    // U(t,2),U(t,3) landed
        __builtin_amdgcn_s_barrier(); SCHEDB;

        // ---- P2: m0-3 x ks1 ----
        Ap += PLANE; Bp += PLANE;
#pragma unroll
        for (int m = 0; m < 4; ++m) af[m] = *(const s16x8*)&Ap[arow + m * 512];
#pragma unroll
        for (int n = 0; n < 4; ++n) bq[n] = *(const s16x8*)&Bp[brow + n * 512];
        stageA(nb, tn, 1);
        LGKMCNT0; SCHEDB;
        __builtin_amdgcn_s_setprio(1);
#pragma unroll
        for (int m = 0; m < 4; ++m)
#pragma unroll
            for (int n = 0; n < 4; ++n)
                acc[m][n] = __builtin_amdgcn_mfma_f32_16x16x32_bf16(af[m], bq[n], acc[m][n], 0, 0, 0);
        __builtin_amdgcn_s_setprio(0); SCHEDB;
        __builtin_amdgcn_s_barrier();

        // ---- P3: m4-7 x ks1 ----
#pragma unroll
        for (int m = 0; m < 4; ++m) af[m] = *(const s16x8*)&Ap[arow + (m + 4) * 512];
        stageB(nb, tn, 1);
        LGKMCNT0; SCHEDB;
        __builtin_amdgcn_s_setprio(1);
#pragma unroll
        for (int m = 0; m < 4; ++m)
#pragma unroll
            for (int n = 0; n < 4; ++n)
                acc[m + 4][n] = __builtin_amdgcn_mfma_f32_16x16x32_bf16(af[m], bq[n], acc[m + 4][n], 0, 0, 0);
        __builtin_amdgcn_s_setprio(0); SCHEDB;
    }
    VMCNT(0);   // drain dummy stages before block retires

    // ---- epilogue: spart[R][nt*4+wn] over this wave's 64 d-cols ----
    int b_idx = mt >> 3;                // 256 rows/tile, 2048/batch
    float Vn[4], Qn[4];
#pragma unroll
    for (int n = 0; n < 4; ++n){
        int D = nt * 256 + wn * 64 + n * 16 + q;
        Vn[n] = V[D];
        Qn[n] = qproj[(size_t)b_idx * HDIM + D];
    }
#pragma unroll
    for (int m = 0; m < 8; ++m){
#pragma unroll
        for (int r = 0; r < 4; ++r){
            float s = 0.f;
#pragma unroll
            for (int n = 0; n < 4; ++n){
                float x = acc[m][n][r] + Qn[n];
                s += Vn[n] * tanh_fast(x);
            }
            s += __shfl_xor(s, 1);
            s += __shfl_xor(s, 2);
            s += __shfl_xor(s, 4);
            s += __shfl_xor(s, 8);
            if (q == 0){
                int R = mt * 256 + wm * 128 + m * 16 + g * 4 + r;
                spart[(size_t)R * 16 + nt * 4 + wn] = s;
            }
        }
    }
}

// ---------------- softmax over S per batch ---------------------------------------
__global__ __launch_bounds__(256) void k_softmax(const float* __restrict__ spart,
                                                 const int* __restrict__ mask,
                                                 float* __restrict__ attn){
    int b = blockIdx.x;
    int tid = threadIdx.x;
    int lane = tid & 63, wv = tid >> 6;
    __shared__ float redmx[4];
    __shared__ float redsm[4];

    float sc[8];
#pragma unroll
    for (int i = 0; i < 8; ++i){
        int s = i * 256 + tid;
        const f32x4* p = (const f32x4*)&spart[(size_t)(b * SEQ + s) * 16];
        f32x4 v0 = p[0], v1 = p[1], v2 = p[2], v3 = p[3];
        float sum = (v0.x + v0.y + v0.z + v0.w) + (v1.x + v1.y + v1.z + v1.w)
                  + (v2.x + v2.y + v2.z + v2.w) + (v3.x + v3.y + v3.z + v3.w);
        sc[i] = (mask[b * SEQ + s] == 0) ? -1e9f : sum;
    }
    float mx = sc[0];
#pragma unroll
    for (int i = 1; i < 8; ++i) mx = fmaxf(mx, sc[i]);
#pragma unroll
    for (int o = 32; o >= 1; o >>= 1) mx = fmaxf(mx, __shfl_xor(mx, o));
    if (lane == 0) redmx[wv] = mx;
    __syncthreads();
    mx = fmaxf(fmaxf(redmx[0], redmx[1]), fmaxf(redmx[2], redmx[3]));

    float ex[8], ssum = 0.f;
#pragma unroll
    for (int i = 0; i < 8; ++i){
        ex[i] = __builtin_amdgcn_exp2f((sc[i] - mx) * 1.4426950408889634f);
        ssum += ex[i];
    }
#pragma unroll
    for (int o = 32; o >= 1; o >>= 1) ssum += __shfl_xor(ssum, o);
    if (lane == 0) redsm[wv] = ssum;
    __syncthreads();
    ssum = redsm[0] + redsm[1] + redsm[2] + redsm[3];
    float inv = 1.0f / ssum;
#pragma unroll
    for (int i = 0; i < 8; ++i)
        attn[(size_t)b * SEQ + i * 256 + tid] = ex[i] * inv;
}

// ---------------- context partials from bf16 keys: cpart[b][32][h] ---------------
__global__ __launch_bounds__(256) void k_ctxpart(const u16* __restrict__ keysbf,
                                                 const float* __restrict__ attn,
                                                 float* __restrict__ cpart){
    int blk = blockIdx.x;                 // 1024 blocks
    int b = blk >> 5, scn = blk & 31;     // 64 rows each
    int t = threadIdx.x;
    f32x4 acc = 0.f;
    const s16x4* kp = (const s16x4*)(keysbf + (size_t)(b * SEQ + scn * 64) * HDIM) + t;
    const float* ap = attn + (size_t)b * SEQ + scn * 64;
#pragma unroll 8
    for (int s = 0; s < 64; ++s){
        float a = ap[s];
        s16x4 kv = kp[(size_t)s * 256];
        f32x4 kf;
        kf.x = __uint_as_float((unsigned)(unsigned short)kv[0] << 16);
        kf.y = __uint_as_float((unsigned)(unsigned short)kv[1] << 16);
        kf.z = __uint_as_float((unsigned)(unsigned short)kv[2] << 16);
        kf.w = __uint_as_float((unsigned)(unsigned short)kv[3] << 16);
        acc += a * kf;
    }
    *(f32x4*)&cpart[(size_t)(b * 32 + scn) * HDIM + t * 4] = acc;
}

__global__ __launch_bounds__(256) void k_ctxred(const float* __restrict__ cpart,
                                                float* __restrict__ ctx){
    int idx = blockIdx.x * 256 + threadIdx.x;   // 128 blocks
    int b = idx >> 10, h = idx & 1023;
    float s = 0.f;
#pragma unroll
    for (int sc = 0; sc < 32; ++sc)
        s += cpart[(size_t)(b * 32 + sc) * HDIM + h];
    ctx[idx] = s;
}

// ---------------- launch ---------------------------------------------------------
extern "C" void kernel_launch(void* const* d_in, const int* in_sizes, int n_in,
                              void* d_out, int out_size, void* d_ws, size_t ws_size,
                              hipStream_t stream){
    (void)in_sizes; (void)n_in; (void)out_size; (void)ws_size;
    const float* query = (const float*)d_in[0];
    const float* keys  = (const float*)d_in[1];
    const int*   mask  = (const int*)d_in[2];
    const float* W1    = (const float*)d_in[3];
    const float* W2    = (const float*)d_in[4];
    const float* V     = (const float*)d_in[5];

    float* ctx_out  = (float*)d_out;            // [32][1024]
    float* attn_out = ctx_out + BATCH * HDIM;   // [32][2048]

    char* ws = (char*)d_ws;
    u16*   W1T   = (u16*)ws;                                   // 2 MB
    float* qproj = (float*)(ws + (2u << 20));                  // 128 KB
    float* spart = (float*)(ws + (2u << 20) + (128u << 10));   // 4 MB
    float* cpart = spart;   // ctxpart partials reuse spart (dead after softmax)
    u16*   keysbf= (u16*)(ws + (9u << 20));                    // 128 MB

    k_w1t    <<<dim3(256),  dim3(256), 0, stream>>>(W1, W1T);
    k_qproj  <<<dim3(512),  dim3(256), 0, stream>>>(query, W2, qproj);
    k_cvt    <<<dim3(2048), dim3(256), 0, stream>>>(keys, keysbf);
    k_score  <<<dim3(1024), dim3(512), 0, stream>>>(keysbf, W1T, qproj, V, spart);
    k_softmax<<<dim3(32),   dim3(256), 0, stream>>>(spart, mask, attn_out);
    k_ctxpart<<<dim3(1024), dim3(256), 0, stream>>>(keysbf, attn_out, cpart);
    k_ctxred <<<dim3(128),  dim3(256), 0, stream>>>(cpart, ctx_out);
}